// Round 1
// baseline (1859.246 us; speedup 1.0000x reference)
//
#include <hip/hip_runtime.h>
#include <math.h>

// B=128 S=512 D=1024 P=32 TEMP=0.1 BETA=0.4
// Strategy: scores via q = wk @ ((0.4*iq+0.6*hq)/(32*0.1)); ctx via (sum_s a_s x_rt[s]) @ wv + (sum a_s) bv.
// Big GEMMs (feat@wf1, h@wf2) in bf16 MFMA, m97-style global_load_lds staging.

typedef short bf16x8 __attribute__((ext_vector_type(8)));
typedef float f32x4 __attribute__((ext_vector_type(4)));

typedef const __attribute__((address_space(1))) void* gp_t;
typedef __attribute__((address_space(3))) void* lp_t;

__device__ __forceinline__ void ld16(const void* g, void* l) {
  __builtin_amdgcn_global_load_lds((gp_t)g, (lp_t)l, 16, 0, 0);
}

__device__ __forceinline__ unsigned short f2b(float f) {
  unsigned int u = __builtin_bit_cast(unsigned int, f);
  u = (u + 0x7FFFu + ((u >> 16) & 1u)) >> 16;   // RNE
  return (unsigned short)u;
}
__device__ __forceinline__ float b2f(unsigned short s) {
  unsigned int u = ((unsigned int)s) << 16;
  return __builtin_bit_cast(float, u);
}
__device__ __forceinline__ float b2f_lo(unsigned int u) { return __builtin_bit_cast(float, u << 16); }
__device__ __forceinline__ float b2f_hi(unsigned int u) { return __builtin_bit_cast(float, u & 0xFFFF0000u); }

// ---- fp32 -> bf16 convert of concat([tail, rel]) into feat [65536][2048] ----
__global__ void cvt_feat_k(const float4* __restrict__ tail, const float4* __restrict__ rel,
                           ushort4* __restrict__ feat) {
  unsigned i = blockIdx.x * 256 + threadIdx.x;          // 2*16777216 total
  const unsigned H = 65536u * 256u;
  bool isrel = i >= H;
  unsigned j = isrel ? (i - H) : i;
  float4 f = isrel ? rel[j] : tail[j];
  unsigned row = j >> 8, c4 = j & 255u;
  ushort4 u4;
  u4.x = f2b(f.x); u4.y = f2b(f.y); u4.z = f2b(f.z); u4.w = f2b(f.w);
  feat[(size_t)row * 512 + (isrel ? 256u : 0u) + c4] = u4;
}

// ---- W [K][N] fp32 -> Wt [N][K] bf16 (tiled transpose) ----
__global__ void transpose_cvt_k(const float* __restrict__ W, unsigned short* __restrict__ Wt,
                                int K, int N) {
  __shared__ float tile[32][33];
  int t = threadIdx.x;
  int tx = t & 31, ty = t >> 5;
  int n0 = blockIdx.x * 32, k0 = blockIdx.y * 32;
  #pragma unroll
  for (int i = 0; i < 32; i += 8)
    tile[ty + i][tx] = W[(size_t)(k0 + ty + i) * N + n0 + tx];
  __syncthreads();
  #pragma unroll
  for (int i = 0; i < 32; i += 8)
    Wt[(size_t)(n0 + ty + i) * K + k0 + tx] = f2b(tile[tx][ty + i]);
}

// ---- small fp32 GEMM, M=128 fixed, N=1024, K-split over grid.y, atomic accumulate ----
// C[m][n] += sum_k (A[m][k] + rs[m]*u[k]) * (transB ? W[n][k] : W[k][n])
struct SJob { const float* A; const float* W; const float* u; const float* rs; float* C; int transB; int pad; };
struct SJobs { SJob j[6]; };

__global__ __launch_bounds__(256) void sgemm_k(SJobs jobs, int K) {
  SJob jb = jobs.j[blockIdx.z];
  __shared__ float At[32 * 132];   // [k][m] (m-stride 132, 16B aligned rows)
  __shared__ float Wt_[32 * 36];   // [k][n]
  int t = threadIdx.x;
  int n0 = blockIdx.x * 32;
  int kchunk = K / gridDim.y;
  int kbase = blockIdx.y * kchunk;
  int tn = t & 7, tm = t >> 3;
  float acc[4][4] = {};
  for (int kt = 0; kt < kchunk; kt += 32) {
    int k0 = kbase + kt;
    #pragma unroll
    for (int i = 0; i < 16; ++i) {
      int f = i * 256 + t;
      int r = f >> 5, c = f & 31;
      float v = jb.A[(size_t)r * K + k0 + c];
      if (jb.u) v += (jb.rs ? jb.rs[r] : 1.0f) * jb.u[k0 + c];
      At[c * 132 + r] = v;
    }
    #pragma unroll
    for (int i = 0; i < 4; ++i) {
      int f = i * 256 + t;
      if (!jb.transB) { int k = f >> 5, n = f & 31; Wt_[k * 36 + n] = jb.W[(size_t)(k0 + k) * 1024 + n0 + n]; }
      else            { int n = f >> 5, k = f & 31; Wt_[k * 36 + n] = jb.W[(size_t)(n0 + n) * K + k0 + k]; }
    }
    __syncthreads();
    #pragma unroll
    for (int kk = 0; kk < 32; ++kk) {
      float4 av = *(const float4*)&At[kk * 132 + tm * 4];
      float4 wv4 = *(const float4*)&Wt_[kk * 36 + tn * 4];
      float ar[4] = {av.x, av.y, av.z, av.w};
      float wr[4] = {wv4.x, wv4.y, wv4.z, wv4.w};
      #pragma unroll
      for (int r = 0; r < 4; ++r)
        #pragma unroll
        for (int c = 0; c < 4; ++c) acc[r][c] += ar[r] * wr[c];
    }
    __syncthreads();
  }
  #pragma unroll
  for (int r = 0; r < 4; ++r)
    #pragma unroll
    for (int c = 0; c < 4; ++c)
      atomicAdd(jb.C + (size_t)(tm * 4 + r) * 1024 + n0 + tn * 4 + c, acc[r][c]);
}

// ---- elementwise: qc = 0.3125*(0.4*iq+0.6*hq); pout = text*sig(tg)+img*sig(ig) ----
__global__ void ew1_k(const float* __restrict__ riq, const float* __restrict__ rhq,
                      const float* __restrict__ rt, const float* __restrict__ ri,
                      const float* __restrict__ rtg, const float* __restrict__ rig,
                      const float* __restrict__ biq, const float* __restrict__ bhq,
                      const float* __restrict__ blt, const float* __restrict__ bli,
                      const float* __restrict__ bgt, const float* __restrict__ bgi,
                      float* __restrict__ qc, float* __restrict__ pout) {
  int idx = blockIdx.x * 256 + threadIdx.x;
  int n = idx & 1023;
  float iq = riq[idx] + biq[n];
  float hq = rhq[idx] + bhq[n];
  qc[idx] = 0.3125f * (0.4f * iq + 0.6f * hq);   // (1/sqrt(1024))/0.1 folded in
  float tg = 1.0f / (1.0f + expf(-(rtg[idx] + bgt[n])));
  float ig = 1.0f / (1.0f + expf(-(rig[idx] + bgi[n])));
  pout[idx] = (rt[idx] + blt[n]) * tg + (ri[idx] + bli[n]) * ig;
}

// ---- c[b] = qc[b]·bk ----
__global__ void cvec_k(const float* __restrict__ qc, const float* __restrict__ bk, float* __restrict__ cv) {
  int b = blockIdx.x, l = threadIdx.x;  // 64 threads
  const float4* a = (const float4*)(qc + (size_t)b * 1024);
  const float4* k4 = (const float4*)bk;
  float acc = 0.f;
  #pragma unroll
  for (int i = 0; i < 4; ++i) {
    float4 x = a[l + i * 64], y = k4[l + i * 64];
    acc += x.x * y.x + x.y * y.y + x.z * y.z + x.w * y.w;
  }
  for (int off = 32; off > 0; off >>= 1) acc += __shfl_down(acc, off);
  if (l == 0) cv[b] = acc;
}

// ---- big bf16 MFMA GEMM: C = act(A @ Wt^T + bias) (+resid), A[M][K], Wt[N][K], bf16 out ----
__global__ __launch_bounds__(256) void gemm_bf16_k(
    const unsigned short* __restrict__ A, const unsigned short* __restrict__ Wt,
    const float* __restrict__ bias, const float* __restrict__ resid,
    unsigned short* __restrict__ C, int M, int N, int K, int act) {
  __shared__ __align__(16) unsigned short As[4096];   // [128][32] bf16, chunk-swizzled
  __shared__ __align__(16) unsigned short Bs[4096];   // [128][32] bf16 (n-major)
  int t = threadIdx.x;
  int l = t & 63, w = t >> 6;
  int m0 = blockIdx.y * 128, n0 = blockIdx.x * 128;
  int wm = (w >> 1) * 64, wn = (w & 1) * 64;

  // staging: thread t covers tile row (t>>2)+{0,64}, swizzled 8-elem chunk
  int srow = t >> 2;
  int scol = ((t & 3) ^ ((t >> 3) & 3)) * 8;
  const unsigned short* Ag = A + (size_t)(m0 + srow) * K + scol;
  const unsigned short* Bg = Wt + (size_t)(n0 + srow) * K + scol;
  unsigned short* AsP = As + t * 8;
  unsigned short* BsP = Bs + t * 8;
  size_t rowadv = (size_t)64 * K;

  // fragment LDS offsets (loop-invariant); phys chunk = q ^ ((row>>1)&3)
  int lm = l & 15, q = l >> 4;
  int aoff[4], boff[4];
  #pragma unroll
  for (int i = 0; i < 4; ++i) {
    int ra = wm + i * 16 + lm;
    aoff[i] = ra * 32 + ((q ^ ((ra >> 1) & 3)) * 8);
    int rb = wn + i * 16 + lm;
    boff[i] = rb * 32 + ((q ^ ((rb >> 1) & 3)) * 8);
  }

  f32x4 acc[4][4];
  #pragma unroll
  for (int i = 0; i < 4; ++i)
    #pragma unroll
    for (int j = 0; j < 4; ++j) acc[i][j] = (f32x4){0.f, 0.f, 0.f, 0.f};

  int kiters = K >> 5;
  for (int kt = 0; kt < kiters; ++kt) {
    const unsigned short* a0 = Ag + kt * 32;
    const unsigned short* b0 = Bg + kt * 32;
    ld16(a0, AsP);
    ld16(a0 + rowadv, AsP + 2048);
    ld16(b0, BsP);
    ld16(b0 + rowadv, BsP + 2048);
    __syncthreads();
    bf16x8 af[4], bfv[4];
    #pragma unroll
    for (int i = 0; i < 4; ++i) af[i] = *(const bf16x8*)(As + aoff[i]);
    #pragma unroll
    for (int i = 0; i < 4; ++i) bfv[i] = *(const bf16x8*)(Bs + boff[i]);
    #pragma unroll
    for (int mi = 0; mi < 4; ++mi)
      #pragma unroll
      for (int ni = 0; ni < 4; ++ni)
        acc[mi][ni] = __builtin_amdgcn_mfma_f32_16x16x32_bf16(af[mi], bfv[ni], acc[mi][ni], 0, 0, 0);
    __syncthreads();
  }

  // epilogue: C/D layout col=lane&15, row=(lane>>4)*4+r
  int lr = (l >> 4) * 4;
  #pragma unroll
  for (int mi = 0; mi < 4; ++mi) {
    #pragma unroll
    for (int ni = 0; ni < 4; ++ni) {
      int gn = n0 + wn + ni * 16 + lm;
      float bb = bias ? bias[gn] : 0.f;
      #pragma unroll
      for (int r = 0; r < 4; ++r) {
        int gm = m0 + wm + mi * 16 + lr + r;
        float v = acc[mi][ni][r] + bb;
        if (act == 1) v = v > 0.f ? v : 0.01f * v;   // leaky_relu 0.01
        if (resid) v += resid[(size_t)gm * N + gn];
        C[(size_t)gm * N + gn] = f2b(v);
      }
    }
  }
}

// ---- scores[b,s] = valid ? x_rt[b,s]·q[b] + c[b] : -inf ; one wave per row ----
__global__ void scores_k(const unsigned short* __restrict__ xrt, const float* __restrict__ q,
                         const float* __restrict__ cv, const float* __restrict__ mask,
                         float* __restrict__ sc) {
  int w = threadIdx.x >> 6, l = threadIdx.x & 63;
  int row = blockIdx.x * 4 + w;
  int b = row >> 9;
  const uint4* xp = (const uint4*)(xrt + (size_t)row * 1024);
  const float4* qp = (const float4*)(q + (size_t)b * 1024);
  float acc = 0.f;
  #pragma unroll
  for (int i = 0; i < 2; ++i) {
    uint4 xa = xp[l * 2 + i];
    float4 q0 = qp[l * 4 + i * 2];
    float4 q1 = qp[l * 4 + i * 2 + 1];
    acc += b2f_lo(xa.x) * q0.x + b2f_hi(xa.x) * q0.y;
    acc += b2f_lo(xa.y) * q0.z + b2f_hi(xa.y) * q0.w;
    acc += b2f_lo(xa.z) * q1.x + b2f_hi(xa.z) * q1.y;
    acc += b2f_lo(xa.w) * q1.z + b2f_hi(xa.w) * q1.w;
  }
  for (int off = 32; off > 0; off >>= 1) acc += __shfl_down(acc, off);
  if (l == 0) sc[row] = (mask[row] > 0.01f) ? (acc + cv[b]) : -__builtin_inff();
}

// ---- per-b softmax, top-32 (no renorm), gather ctx_rt = sum a_s * x_rt[s], asum ----
__global__ __launch_bounds__(256) void topk_ctx_k(const float* __restrict__ sc,
                                                  const unsigned short* __restrict__ xrt,
                                                  float* __restrict__ ctxrt, float* __restrict__ asum) {
  int b = blockIdx.x, t = threadIdx.x;
  __shared__ float sv[512];
  __shared__ float red[256];
  __shared__ int redi[256];
  __shared__ float topw[32];
  __shared__ int topi[32];
  sv[t] = sc[b * 512 + t];
  sv[t + 256] = sc[b * 512 + 256 + t];
  __syncthreads();
  red[t] = fmaxf(sv[t], sv[t + 256]);
  __syncthreads();
  for (int s = 128; s > 0; s >>= 1) { if (t < s) red[t] = fmaxf(red[t], red[t + s]); __syncthreads(); }
  float mx = red[0];
  __syncthreads();
  float e0 = expf(sv[t] - mx), e1 = expf(sv[t + 256] - mx);
  red[t] = e0 + e1;
  __syncthreads();
  for (int s = 128; s > 0; s >>= 1) { if (t < s) red[t] += red[t + s]; __syncthreads(); }
  float inv = 1.0f / red[0];
  __syncthreads();
  sv[t] = e0 * inv; sv[t + 256] = e1 * inv;
  __syncthreads();
  for (int it = 0; it < 32; ++it) {
    float v0 = sv[t], v1 = sv[t + 256];
    float bv_; int bi;
    if (v1 > v0) { bv_ = v1; bi = t + 256; } else { bv_ = v0; bi = t; }  // tie -> smaller idx
    red[t] = bv_; redi[t] = bi;
    __syncthreads();
    for (int s = 128; s > 0; s >>= 1) {
      if (t < s) {
        if (red[t + s] > red[t] || (red[t + s] == red[t] && redi[t + s] < redi[t])) {
          red[t] = red[t + s]; redi[t] = redi[t + s];
        }
      }
      __syncthreads();
    }
    if (t == 0) { topw[it] = red[0]; topi[it] = redi[0]; sv[redi[0]] = -1.0f; }
    __syncthreads();
  }
  #pragma unroll
  for (int dd = 0; dd < 4; ++dd) {
    int d = t + dd * 256;
    float acc = 0.f;
    for (int j = 0; j < 32; ++j)
      acc += topw[j] * b2f(xrt[(size_t)(b * 512 + topi[j]) * 1024 + d]);
    ctxrt[(size_t)b * 1024 + d] = acc;
  }
  if (t == 0) {
    float s = 0.f;
    for (int j = 0; j < 32; ++j) s += topw[j];
    asum[b] = s;
  }
}

// ---- out = rawL3 + bltr + pout ----
__global__ void ew2_k(const float* __restrict__ r3, const float* __restrict__ bltr,
                      const float* __restrict__ pout, float* __restrict__ out) {
  int idx = blockIdx.x * 256 + threadIdx.x;
  out[idx] = r3[idx] + bltr[idx & 1023] + pout[idx];
}

extern "C" void kernel_launch(void* const* d_in, const int* in_sizes, int n_in,
                              void* d_out, int out_size, void* d_ws, size_t ws_size,
                              hipStream_t stream) {
  const float* x_head = (const float*)d_in[0];
  const float* x_rel  = (const float*)d_in[1];
  const float* x_tail = (const float*)d_in[2];
  const float* x_mask = (const float*)d_in[3];
  const float* x_img  = (const float*)d_in[4];
  const float* wf1 = (const float*)d_in[5];  const float* bf1 = (const float*)d_in[6];
  const float* wf2 = (const float*)d_in[7];  const float* bf2 = (const float*)d_in[8];
  const float* wk  = (const float*)d_in[9];  const float* bk  = (const float*)d_in[10];
  const float* wv  = (const float*)d_in[11]; const float* bv  = (const float*)d_in[12];
  const float* wp  = (const float*)d_in[13]; const float* bp  = (const float*)d_in[14];
  const float* wiq = (const float*)d_in[15]; const float* biq = (const float*)d_in[16];
  const float* whq = (const float*)d_in[17]; const float* bhq = (const float*)d_in[18];
  const float* wlt = (const float*)d_in[19]; const float* blt = (const float*)d_in[20];
  const float* wli = (const float*)d_in[21]; const float* bli = (const float*)d_in[22];
  const float* wltr= (const float*)d_in[23]; const float* bltr= (const float*)d_in[24];
  const float* wgt = (const float*)d_in[25]; const float* bgt = (const float*)d_in[26];
  const float* wgi = (const float*)d_in[27]; const float* bgi = (const float*)d_in[28];
  float* out = (float*)d_out;
  char* ws = (char*)d_ws;

  // workspace layout (bytes); xrt overlays feat (dead after GEMM1). total ~397 MiB
  unsigned short* feat = (unsigned short*)(ws);                       // 268435456
  unsigned short* hbuf = (unsigned short*)(ws + 268435456ull);        // 134217728
  unsigned short* wf1t = (unsigned short*)(ws + 402653184ull);        // 4194304
  unsigned short* wf2t = (unsigned short*)(ws + 406847488ull);        // 2097152
  char* z = ws + 408944640ull;                                        // 10 x 512KB zeroed
  float* raw_iq = (float*)(z);
  float* raw_hq = (float*)(z + 524288);
  float* raw_t  = (float*)(z + 1048576);
  float* raw_i  = (float*)(z + 1572864);
  float* raw_tg = (float*)(z + 2097152);
  float* raw_ig = (float*)(z + 2621440);
  float* raw_q  = (float*)(z + 3145728);
  float* rawL1  = (float*)(z + 3670016);
  float* rawL2  = (float*)(z + 4194304);
  float* rawL3  = (float*)(z + 4718592);
  float* qc    = (float*)(ws + 414187520ull);
  float* pout  = (float*)(ws + 414711808ull);
  float* cv    = (float*)(ws + 415236096ull);
  float* sc    = (float*)(ws + 415236608ull);
  float* ctxrt = (float*)(ws + 415498752ull);
  float* asum  = (float*)(ws + 416023040ull);
  unsigned short* xrt = (unsigned short*)(ws);   // bf16 [65536][1024]

  hipMemsetAsync(z, 0, 5242880, stream);

  cvt_feat_k<<<131072, 256, 0, stream>>>((const float4*)x_tail, (const float4*)x_rel, (ushort4*)feat);
  transpose_cvt_k<<<dim3(32, 64), 256, 0, stream>>>(wf1, wf1t, 2048, 1024);
  transpose_cvt_k<<<dim3(32, 32), 256, 0, stream>>>(wf2, wf2t, 1024, 1024);

  SJobs j6 = {};
  j6.j[0] = SJob{x_img,  wiq, nullptr, nullptr, raw_iq, 0, 0};
  j6.j[1] = SJob{x_head, whq, nullptr, nullptr, raw_hq, 0, 0};
  j6.j[2] = SJob{x_head, wlt, nullptr, nullptr, raw_t,  0, 0};
  j6.j[3] = SJob{x_img,  wli, nullptr, nullptr, raw_i,  0, 0};
  j6.j[4] = SJob{x_head, wgt, nullptr, nullptr, raw_tg, 0, 0};
  j6.j[5] = SJob{x_img,  wgi, nullptr, nullptr, raw_ig, 0, 0};
  sgemm_k<<<dim3(32, 2, 6), 256, 0, stream>>>(j6, 1024);

  ew1_k<<<512, 256, 0, stream>>>(raw_iq, raw_hq, raw_t, raw_i, raw_tg, raw_ig,
                                 biq, bhq, blt, bli, bgt, bgi, qc, pout);

  SJobs jq = {};
  jq.j[0] = SJob{qc, wk, nullptr, nullptr, raw_q, 1, 0};   // q = qc @ wk^T
  sgemm_k<<<dim3(32, 4, 1), 256, 0, stream>>>(jq, 1024);
  cvec_k<<<128, 64, 0, stream>>>(qc, bk, cv);

  // h = leaky(feat @ wf1 + bf1); x_rt = tail + (h @ wf2 + bf2)
  gemm_bf16_k<<<dim3(8, 512), 256, 0, stream>>>(feat, wf1t, bf1, nullptr, hbuf, 65536, 1024, 2048, 1);
  gemm_bf16_k<<<dim3(8, 512), 256, 0, stream>>>(hbuf, wf2t, bf2, x_tail, xrt, 65536, 1024, 1024, 0);

  scores_k<<<16384, 256, 0, stream>>>(xrt, raw_q, cv, x_mask, sc);
  topk_ctx_k<<<128, 256, 0, stream>>>(sc, xrt, ctxrt, asum);

  SJobs jl = {};
  jl.j[0] = SJob{ctxrt, wv, nullptr, nullptr, rawL1, 0, 0};          // raw ctx (pre +asum*bv)
  sgemm_k<<<dim3(32, 4, 1), 256, 0, stream>>>(jl, 1024);
  jl.j[0] = SJob{rawL1, wp, bv, asum, rawL2, 0, 0};                  // A_eff = rawL1 + asum*bv
  sgemm_k<<<dim3(32, 4, 1), 256, 0, stream>>>(jl, 1024);
  jl.j[0] = SJob{rawL2, wltr, bp, nullptr, rawL3, 0, 0};             // A_eff = rawL2 + bp
  sgemm_k<<<dim3(32, 4, 1), 256, 0, stream>>>(jl, 1024);
  ew2_k<<<512, 256, 0, stream>>>(rawL3, bltr, pout, out);
}

// Round 2
// 1678.843 us; speedup vs baseline: 1.1075x; 1.1075x over previous
//
#include <hip/hip_runtime.h>
#include <math.h>

// B=128 S=512 D=1024 P=32 TEMP=0.1 BETA=0.4
// scores via q = wk @ ((0.4*iq+0.6*hq)/(32*0.1)); ctx via (sum_s a_s x_rt[s]) @ wv + (sum a_s) bv.
// Big GEMMs bf16 MFMA m97-style; XCD-aware swizzle (same A-panel -> same XCD);
// LDS-staged epilogue with 16B stores.

typedef short bf16x8 __attribute__((ext_vector_type(8)));
typedef float f32x4 __attribute__((ext_vector_type(4)));

typedef const __attribute__((address_space(1))) void* gp_t;
typedef __attribute__((address_space(3))) void* lp_t;

__device__ __forceinline__ void ld16(const void* g, void* l) {
  __builtin_amdgcn_global_load_lds((gp_t)g, (lp_t)l, 16, 0, 0);
}

__device__ __forceinline__ unsigned int f2b(float f) {
  unsigned int u = __builtin_bit_cast(unsigned int, f);
  u = (u + 0x7FFFu + ((u >> 16) & 1u)) >> 16;   // RNE
  return u & 0xFFFFu;
}
__device__ __forceinline__ float b2f(unsigned short s) {
  unsigned int u = ((unsigned int)s) << 16;
  return __builtin_bit_cast(float, u);
}
__device__ __forceinline__ float b2f_lo(unsigned int u) { return __builtin_bit_cast(float, u << 16); }
__device__ __forceinline__ float b2f_hi(unsigned int u) { return __builtin_bit_cast(float, u & 0xFFFF0000u); }
__device__ __forceinline__ unsigned int pack2(float lo, float hi) { return f2b(lo) | (f2b(hi) << 16); }

// ---- fp32 -> bf16 convert of concat([tail, rel]) into feat [65536][2048], 16B ld/st ----
__global__ void cvt_feat_k(const float4* __restrict__ tail, const float4* __restrict__ rel,
                           uint4* __restrict__ feat) {
  unsigned i = blockIdx.x * 256 + threadIdx.x;     // one 8-elem bf16 chunk each; 16.7M total
  unsigned row = i >> 8, c = i & 255u;             // 256 chunks per feat row
  bool isrel = c >= 128u;
  const float4* src = isrel ? rel : tail;
  unsigned s = row * 256u + (c & 127u) * 2u;
  float4 a = src[s], b = src[s + 1];
  uint4 o;
  o.x = pack2(a.x, a.y); o.y = pack2(a.z, a.w);
  o.z = pack2(b.x, b.y); o.w = pack2(b.z, b.w);
  feat[i] = o;
}

// ---- W [K][N] fp32 -> Wt [N][K] bf16 (tiled transpose) ----
__global__ void transpose_cvt_k(const float* __restrict__ W, unsigned short* __restrict__ Wt,
                                int K, int N) {
  __shared__ float tile[32][33];
  int t = threadIdx.x;
  int tx = t & 31, ty = t >> 5;
  int n0 = blockIdx.x * 32, k0 = blockIdx.y * 32;
  #pragma unroll
  for (int i = 0; i < 32; i += 8)
    tile[ty + i][tx] = W[(size_t)(k0 + ty + i) * N + n0 + tx];
  __syncthreads();
  #pragma unroll
  for (int i = 0; i < 32; i += 8)
    Wt[(size_t)(n0 + ty + i) * K + k0 + tx] = (unsigned short)f2b(tile[tx][ty + i]);
}

// ---- small fp32 GEMM, M=128 fixed, N=1024, K-split over grid.y, atomic accumulate ----
// C[m][n] += sum_k (A[m][k] + rs[m]*u[k]) * (transB ? W[n][k] : W[k][n])
struct SJob { const float* A; const float* W; const float* u; const float* rs; float* C; int transB; int pad; };
struct SJobs { SJob j[6]; };

__global__ __launch_bounds__(256) void sgemm_k(SJobs jobs, int K) {
  SJob jb = jobs.j[blockIdx.z];
  __shared__ float At[32 * 132];   // [k][m]
  __shared__ float Wt_[32 * 36];   // [k][n]
  int t = threadIdx.x;
  int n0 = blockIdx.x * 32;
  int kchunk = K / gridDim.y;
  int kbase = blockIdx.y * kchunk;
  int tn = t & 7, tm = t >> 3;
  float acc[4][4] = {};
  for (int kt = 0; kt < kchunk; kt += 32) {
    int k0 = kbase + kt;
    #pragma unroll
    for (int i = 0; i < 16; ++i) {
      int f = i * 256 + t;
      int r = f >> 5, c = f & 31;
      float v = jb.A[(size_t)r * K + k0 + c];
      if (jb.u) v += (jb.rs ? jb.rs[r] : 1.0f) * jb.u[k0 + c];
      At[c * 132 + r] = v;
    }
    #pragma unroll
    for (int i = 0; i < 4; ++i) {
      int f = i * 256 + t;
      if (!jb.transB) { int k = f >> 5, n = f & 31; Wt_[k * 36 + n] = jb.W[(size_t)(k0 + k) * 1024 + n0 + n]; }
      else            { int n = f >> 5, k = f & 31; Wt_[k * 36 + n] = jb.W[(size_t)(n0 + n) * K + k0 + k]; }
    }
    __syncthreads();
    #pragma unroll
    for (int kk = 0; kk < 32; ++kk) {
      float4 av = *(const float4*)&At[kk * 132 + tm * 4];
      float4 wv4 = *(const float4*)&Wt_[kk * 36 + tn * 4];
      float ar[4] = {av.x, av.y, av.z, av.w};
      float wr[4] = {wv4.x, wv4.y, wv4.z, wv4.w};
      #pragma unroll
      for (int r = 0; r < 4; ++r)
        #pragma unroll
        for (int c = 0; c < 4; ++c) acc[r][c] += ar[r] * wr[c];
    }
    __syncthreads();
  }
  #pragma unroll
  for (int r = 0; r < 4; ++r)
    #pragma unroll
    for (int c = 0; c < 4; ++c)
      atomicAdd(jb.C + (size_t)(tm * 4 + r) * 1024 + n0 + tn * 4 + c, acc[r][c]);
}

// ---- elementwise: qc = 0.3125*(0.4*iq+0.6*hq); pout = text*sig(tg)+img*sig(ig) ----
__global__ void ew1_k(const float* __restrict__ riq, const float* __restrict__ rhq,
                      const float* __restrict__ rt, const float* __restrict__ ri,
                      const float* __restrict__ rtg, const float* __restrict__ rig,
                      const float* __restrict__ biq, const float* __restrict__ bhq,
                      const float* __restrict__ blt, const float* __restrict__ bli,
                      const float* __restrict__ bgt, const float* __restrict__ bgi,
                      float* __restrict__ qc, float* __restrict__ pout) {
  int idx = blockIdx.x * 256 + threadIdx.x;
  int n = idx & 1023;
  float iq = riq[idx] + biq[n];
  float hq = rhq[idx] + bhq[n];
  qc[idx] = 0.3125f * (0.4f * iq + 0.6f * hq);
  float tg = 1.0f / (1.0f + expf(-(rtg[idx] + bgt[n])));
  float ig = 1.0f / (1.0f + expf(-(rig[idx] + bgi[n])));
  pout[idx] = (rt[idx] + blt[n]) * tg + (ri[idx] + bli[n]) * ig;
}

// ---- c[b] = qc[b]·bk ----
__global__ void cvec_k(const float* __restrict__ qc, const float* __restrict__ bk, float* __restrict__ cv) {
  int b = blockIdx.x, l = threadIdx.x;  // 64 threads
  const float4* a = (const float4*)(qc + (size_t)b * 1024);
  const float4* k4 = (const float4*)bk;
  float acc = 0.f;
  #pragma unroll
  for (int i = 0; i < 4; ++i) {
    float4 x = a[l + i * 64], y = k4[l + i * 64];
    acc += x.x * y.x + x.y * y.y + x.z * y.z + x.w * y.w;
  }
  for (int off = 32; off > 0; off >>= 1) acc += __shfl_down(acc, off);
  if (l == 0) cv[b] = acc;
}

// ---- big bf16 MFMA GEMM: C = act(A @ Wt^T + bias) (+resid), A[M][K], Wt[N][K], bf16 out ----
// N must be 1024 (8 n-tiles). 1D grid = (M/128)*8, XCD-swizzled: m_tile = (L>>3)*... see below.
__global__ __launch_bounds__(256) void gemm_bf16_k(
    const unsigned short* __restrict__ A, const unsigned short* __restrict__ Wt,
    const float* __restrict__ bias, const float* __restrict__ resid,
    unsigned short* __restrict__ C, int M, int N, int K, int act) {
  __shared__ __align__(16) unsigned short Sm[16384];   // As[4096] | Bs[4096], reused as Cs[16384]
  unsigned short* As = Sm;
  unsigned short* Bs = Sm + 4096;
  int t = threadIdx.x;
  int l = t & 63, w = t >> 6;

  // XCD swizzle: all 8 n-tiles of one m-panel share L%8 -> same XCD (round-robin assumption;
  // wrong mapping only costs speed, not correctness).
  int L = blockIdx.x;
  int xcd = L & 7, j = L >> 3;
  int n_t = j & 7;
  int m_t = (j >> 3) * 8 + xcd;
  int m0 = m_t * 128, n0 = n_t * 128;
  int wm = (w >> 1) * 64, wn = (w & 1) * 64;

  // staging: thread t covers tile row (t>>2)+{0,64}, swizzled 8-elem chunk
  int srow = t >> 2;
  int scol = ((t & 3) ^ ((t >> 3) & 3)) * 8;
  const unsigned short* Ag = A + (size_t)(m0 + srow) * K + scol;
  const unsigned short* Bg = Wt + (size_t)(n0 + srow) * K + scol;
  unsigned short* AsP = As + t * 8;
  unsigned short* BsP = Bs + t * 8;
  size_t rowadv = (size_t)64 * K;

  int lm = l & 15, q = l >> 4;
  int aoff[4], boff[4];
  #pragma unroll
  for (int i = 0; i < 4; ++i) {
    int ra = wm + i * 16 + lm;
    aoff[i] = ra * 32 + ((q ^ ((ra >> 1) & 3)) * 8);
    int rb = wn + i * 16 + lm;
    boff[i] = rb * 32 + ((q ^ ((rb >> 1) & 3)) * 8);
  }

  f32x4 acc[4][4];
  #pragma unroll
  for (int i = 0; i < 4; ++i)
    #pragma unroll
    for (int jj = 0; jj < 4; ++jj) acc[i][jj] = (f32x4){0.f, 0.f, 0.f, 0.f};

  int kiters = K >> 5;
  for (int kt = 0; kt < kiters; ++kt) {
    const unsigned short* a0 = Ag + kt * 32;
    const unsigned short* b0 = Bg + kt * 32;
    ld16(a0, AsP);
    ld16(a0 + rowadv, AsP + 2048);
    ld16(b0, BsP);
    ld16(b0 + rowadv, BsP + 2048);
    __syncthreads();
    bf16x8 af[4], bfv[4];
    #pragma unroll
    for (int i = 0; i < 4; ++i) af[i] = *(const bf16x8*)(As + aoff[i]);
    #pragma unroll
    for (int i = 0; i < 4; ++i) bfv[i] = *(const bf16x8*)(Bs + boff[i]);
    #pragma unroll
    for (int mi = 0; mi < 4; ++mi)
      #pragma unroll
      for (int ni = 0; ni < 4; ++ni)
        acc[mi][ni] = __builtin_amdgcn_mfma_f32_16x16x32_bf16(af[mi], bfv[ni], acc[mi][ni], 0, 0, 0);
    __syncthreads();
  }

  // ---- epilogue phase 1: bias+act, pack bf16 tile into LDS (C/D: col=lane&15, row=(l>>4)*4+r)
  int lr = q * 4;
  #pragma unroll
  for (int mi = 0; mi < 4; ++mi) {
    #pragma unroll
    for (int ni = 0; ni < 4; ++ni) {
      int cn = wn + ni * 16 + lm;
      float bb = bias ? bias[n0 + cn] : 0.f;
      #pragma unroll
      for (int r = 0; r < 4; ++r) {
        int cm = wm + mi * 16 + lr + r;
        float v = acc[mi][ni][r] + bb;
        if (act == 1) v = v > 0.f ? v : 0.01f * v;   // leaky_relu 0.01
        Sm[cm * 128 + cn] = (unsigned short)f2b(v);
      }
    }
  }
  __syncthreads();

  // ---- epilogue phase 2: coalesced 16B stores (+vectorized fp32 resid)
  #pragma unroll
  for (int p = 0; p < 8; ++p) {
    int idx = p * 256 + t;
    int row = idx >> 4;
    int col8 = (idx & 15) * 8;
    uint4 cs = *(const uint4*)(Sm + row * 128 + col8);
    size_t go = (size_t)(m0 + row) * N + n0 + col8;
    uint4 o;
    if (resid) {
      float4 r0 = *(const float4*)(resid + go);
      float4 r1 = *(const float4*)(resid + go + 4);
      o.x = pack2(b2f_lo(cs.x) + r0.x, b2f_hi(cs.x) + r0.y);
      o.y = pack2(b2f_lo(cs.y) + r0.z, b2f_hi(cs.y) + r0.w);
      o.z = pack2(b2f_lo(cs.z) + r1.x, b2f_hi(cs.z) + r1.y);
      o.w = pack2(b2f_lo(cs.w) + r1.z, b2f_hi(cs.w) + r1.w);
    } else {
      o = cs;
    }
    *(uint4*)(C + go) = o;
  }
}

// ---- scores[b,s] = valid ? x_rt[b,s]·q[b] + c[b] : -inf ; one wave per row ----
__global__ void scores_k(const unsigned short* __restrict__ xrt, const float* __restrict__ q,
                         const float* __restrict__ cv, const float* __restrict__ mask,
                         float* __restrict__ sc) {
  int w = threadIdx.x >> 6, l = threadIdx.x & 63;
  int row = blockIdx.x * 4 + w;
  int b = row >> 9;
  const uint4* xp = (const uint4*)(xrt + (size_t)row * 1024);
  const float4* qp = (const float4*)(q + (size_t)b * 1024);
  float acc = 0.f;
  #pragma unroll
  for (int i = 0; i < 2; ++i) {
    uint4 xa = xp[l * 2 + i];
    float4 q0 = qp[l * 4 + i * 2];
    float4 q1 = qp[l * 4 + i * 2 + 1];
    acc += b2f_lo(xa.x) * q0.x + b2f_hi(xa.x) * q0.y;
    acc += b2f_lo(xa.y) * q0.z + b2f_hi(xa.y) * q0.w;
    acc += b2f_lo(xa.z) * q1.x + b2f_hi(xa.z) * q1.y;
    acc += b2f_lo(xa.w) * q1.z + b2f_hi(xa.w) * q1.w;
  }
  for (int off = 32; off > 0; off >>= 1) acc += __shfl_down(acc, off);
  if (l == 0) sc[row] = (mask[row] > 0.01f) ? (acc + cv[b]) : -__builtin_inff();
}

// ---- per-b softmax, top-32 (no renorm), gather ctx_rt = sum a_s * x_rt[s], asum ----
__global__ __launch_bounds__(256) void topk_ctx_k(const float* __restrict__ sc,
                                                  const unsigned short* __restrict__ xrt,
                                                  float* __restrict__ ctxrt, float* __restrict__ asum) {
  int b = blockIdx.x, t = threadIdx.x;
  __shared__ float sv[512];
  __shared__ float red[256];
  __shared__ int redi[256];
  __shared__ float topw[32];
  __shared__ int topi[32];
  sv[t] = sc[b * 512 + t];
  sv[t + 256] = sc[b * 512 + 256 + t];
  __syncthreads();
  red[t] = fmaxf(sv[t], sv[t + 256]);
  __syncthreads();
  for (int s = 128; s > 0; s >>= 1) { if (t < s) red[t] = fmaxf(red[t], red[t + s]); __syncthreads(); }
  float mx = red[0];
  __syncthreads();
  float e0 = expf(sv[t] - mx), e1 = expf(sv[t + 256] - mx);
  red[t] = e0 + e1;
  __syncthreads();
  for (int s = 128; s > 0; s >>= 1) { if (t < s) red[t] += red[t + s]; __syncthreads(); }
  float inv = 1.0f / red[0];
  __syncthreads();
  sv[t] = e0 * inv; sv[t + 256] = e1 * inv;
  __syncthreads();
  for (int it = 0; it < 32; ++it) {
    float v0 = sv[t], v1 = sv[t + 256];
    float bv_; int bi;
    if (v1 > v0) { bv_ = v1; bi = t + 256; } else { bv_ = v0; bi = t; }
    red[t] = bv_; redi[t] = bi;
    __syncthreads();
    for (int s = 128; s > 0; s >>= 1) {
      if (t < s) {
        if (red[t + s] > red[t] || (red[t + s] == red[t] && redi[t + s] < redi[t])) {
          red[t] = red[t + s]; redi[t] = redi[t + s];
        }
      }
      __syncthreads();
    }
    if (t == 0) { topw[it] = red[0]; topi[it] = redi[0]; sv[redi[0]] = -1.0f; }
    __syncthreads();
  }
  #pragma unroll
  for (int dd = 0; dd < 4; ++dd) {
    int d = t + dd * 256;
    float acc = 0.f;
    for (int j = 0; j < 32; ++j)
      acc += topw[j] * b2f(xrt[(size_t)(b * 512 + topi[j]) * 1024 + d]);
    ctxrt[(size_t)b * 1024 + d] = acc;
  }
  if (t == 0) {
    float s = 0.f;
    for (int j = 0; j < 32; ++j) s += topw[j];
    asum[b] = s;
  }
}

// ---- out = rawL3 + bltr + pout ----
__global__ void ew2_k(const float* __restrict__ r3, const float* __restrict__ bltr,
                      const float* __restrict__ pout, float* __restrict__ out) {
  int idx = blockIdx.x * 256 + threadIdx.x;
  out[idx] = r3[idx] + bltr[idx & 1023] + pout[idx];
}

extern "C" void kernel_launch(void* const* d_in, const int* in_sizes, int n_in,
                              void* d_out, int out_size, void* d_ws, size_t ws_size,
                              hipStream_t stream) {
  const float* x_head = (const float*)d_in[0];
  const float* x_rel  = (const float*)d_in[1];
  const float* x_tail = (const float*)d_in[2];
  const float* x_mask = (const float*)d_in[3];
  const float* x_img  = (const float*)d_in[4];
  const float* wf1 = (const float*)d_in[5];  const float* bf1 = (const float*)d_in[6];
  const float* wf2 = (const float*)d_in[7];  const float* bf2 = (const float*)d_in[8];
  const float* wk  = (const float*)d_in[9];  const float* bk  = (const float*)d_in[10];
  const float* wv  = (const float*)d_in[11]; const float* bv  = (const float*)d_in[12];
  const float* wp  = (const float*)d_in[13]; const float* bp  = (const float*)d_in[14];
  const float* wiq = (const float*)d_in[15]; const float* biq = (const float*)d_in[16];
  const float* whq = (const float*)d_in[17]; const float* bhq = (const float*)d_in[18];
  const float* wlt = (const float*)d_in[19]; const float* blt = (const float*)d_in[20];
  const float* wli = (const float*)d_in[21]; const float* bli = (const float*)d_in[22];
  const float* wltr= (const float*)d_in[23]; const float* bltr= (const float*)d_in[24];
  const float* wgt = (const float*)d_in[25]; const float* bgt = (const float*)d_in[26];
  const float* wgi = (const float*)d_in[27]; const float* bgi = (const float*)d_in[28];
  float* out = (float*)d_out;
  char* ws = (char*)d_ws;

  // workspace layout (bytes); xrt overlays feat (dead after GEMM1). total ~397 MiB
  unsigned short* feat = (unsigned short*)(ws);                       // 268435456
  unsigned short* hbuf = (unsigned short*)(ws + 268435456ull);        // 134217728
  unsigned short* wf1t = (unsigned short*)(ws + 402653184ull);        // 4194304
  unsigned short* wf2t = (unsigned short*)(ws + 406847488ull);        // 2097152
  char* z = ws + 408944640ull;                                        // 10 x 512KB zeroed
  float* raw_iq = (float*)(z);
  float* raw_hq = (float*)(z + 524288);
  float* raw_t  = (float*)(z + 1048576);
  float* raw_i  = (float*)(z + 1572864);
  float* raw_tg = (float*)(z + 2097152);
  float* raw_ig = (float*)(z + 2621440);
  float* raw_q  = (float*)(z + 3145728);
  float* rawL1  = (float*)(z + 3670016);
  float* rawL2  = (float*)(z + 4194304);
  float* rawL3  = (float*)(z + 4718592);
  float* qc    = (float*)(ws + 414187520ull);
  float* pout  = (float*)(ws + 414711808ull);
  float* cv    = (float*)(ws + 415236096ull);
  float* sc    = (float*)(ws + 415236608ull);
  float* ctxrt = (float*)(ws + 415498752ull);
  float* asum  = (float*)(ws + 416023040ull);
  unsigned short* xrt = (unsigned short*)(ws);   // bf16 [65536][1024]

  hipMemsetAsync(z, 0, 5242880, stream);

  cvt_feat_k<<<65536, 256, 0, stream>>>((const float4*)x_tail, (const float4*)x_rel, (uint4*)feat);
  transpose_cvt_k<<<dim3(32, 64), 256, 0, stream>>>(wf1, wf1t, 2048, 1024);
  transpose_cvt_k<<<dim3(32, 32), 256, 0, stream>>>(wf2, wf2t, 1024, 1024);

  SJobs j6 = {};
  j6.j[0] = SJob{x_img,  wiq, nullptr, nullptr, raw_iq, 0, 0};
  j6.j[1] = SJob{x_head, whq, nullptr, nullptr, raw_hq, 0, 0};
  j6.j[2] = SJob{x_head, wlt, nullptr, nullptr, raw_t,  0, 0};
  j6.j[3] = SJob{x_img,  wli, nullptr, nullptr, raw_i,  0, 0};
  j6.j[4] = SJob{x_head, wgt, nullptr, nullptr, raw_tg, 0, 0};
  j6.j[5] = SJob{x_img,  wgi, nullptr, nullptr, raw_ig, 0, 0};
  sgemm_k<<<dim3(32, 2, 6), 256, 0, stream>>>(j6, 1024);

  ew1_k<<<512, 256, 0, stream>>>(raw_iq, raw_hq, raw_t, raw_i, raw_tg, raw_ig,
                                 biq, bhq, blt, bli, bgt, bgi, qc, pout);

  SJobs jq = {};
  jq.j[0] = SJob{qc, wk, nullptr, nullptr, raw_q, 1, 0};   // q = qc @ wk^T
  sgemm_k<<<dim3(32, 4, 1), 256, 0, stream>>>(jq, 1024);
  cvec_k<<<128, 64, 0, stream>>>(qc, bk, cv);

  // h = leaky(feat @ wf1 + bf1); x_rt = tail + (h @ wf2 + bf2)
  gemm_bf16_k<<<4096, 256, 0, stream>>>(feat, wf1t, bf1, nullptr, hbuf, 65536, 1024, 2048, 1);
  gemm_bf16_k<<<4096, 256, 0, stream>>>(hbuf, wf2t, bf2, x_tail, xrt, 65536, 1024, 1024, 0);

  scores_k<<<16384, 256, 0, stream>>>(xrt, raw_q, cv, x_mask, sc);
  topk_ctx_k<<<128, 256, 0, stream>>>(sc, xrt, ctxrt, asum);

  SJobs jl = {};
  jl.j[0] = SJob{ctxrt, wv, nullptr, nullptr, rawL1, 0, 0};          // raw ctx (pre +asum*bv)
  sgemm_k<<<dim3(32, 4, 1), 256, 0, stream>>>(jl, 1024);
  jl.j[0] = SJob{rawL1, wp, bv, asum, rawL2, 0, 0};                  // A_eff = rawL1 + asum*bv
  sgemm_k<<<dim3(32, 4, 1), 256, 0, stream>>>(jl, 1024);
  jl.j[0] = SJob{rawL2, wltr, bp, nullptr, rawL3, 0, 0};             // A_eff = rawL2 + bp
  sgemm_k<<<dim3(32, 4, 1), 256, 0, stream>>>(jl, 1024);
  ew2_k<<<512, 256, 0, stream>>>(rawL3, bltr, pout, out);
}